// Round 1
// baseline (209.133 us; speedup 1.0000x reference)
//
#include <hip/hip_runtime.h>
#include <hip/hip_bf16.h>

// ---------------------------------------------------------------------------
// TwoSimplicialAttention  (B=2, T=192, C=512, H=8, D=64)
// R5: attn occupancy fix: K2s LDS staging removed (k2 read direct from
//     global with depth-1 register prefetch; 16-lane broadcast, L1/L2-hit).
//     LDS 58368 -> 52224 => 3 blocks/CU, grid 768 = 3*256 fully resident
//     (removes the 512+256 two-pass tail). launch_bounds (256,3).
//     Everything else identical to R4.
// ---------------------------------------------------------------------------

typedef float  v4f __attribute__((ext_vector_type(4)));
typedef short  v8s __attribute__((ext_vector_type(8)));

__device__ __forceinline__ unsigned short f2bf(float f) {
  unsigned u = __float_as_uint(f);
  u += 0x7fffu + ((u >> 16) & 1u);       // RNE
  return (unsigned short)(u >> 16);
}
__device__ __forceinline__ float bf2f(unsigned short b) {
  return __uint_as_float(((unsigned)b) << 16);
}
__device__ __forceinline__ unsigned pack_bf16(float lo, float hi) {
  __hip_bfloat162 t = __float22bfloat162_rn(float2{lo, hi});
  union { __hip_bfloat162 b; unsigned u; } cv;
  cv.b = t;
  return cv.u;
}

#if __has_builtin(__builtin_amdgcn_exp2f)
#define EXP2F(x) __builtin_amdgcn_exp2f(x)
#else
#define EXP2F(x) exp2f(x)
#endif

#define MFMA32(a, b, c) __builtin_amdgcn_mfma_f32_16x16x32_bf16((a), (b), (c), 0, 0, 0)

// q scale = D^-0.5 * log2(e)
#define QSCALE 0.18033688011112042f

// ws layout, floats (wsf):
//   qs   [16][192][64]        @ 0        (q * 0.125*log2e, fp32)
//   v2p  [16][192][16][4]     @ 196608   ([.][k][c][r] = v2[d=c+16r], fp32)
//   accp [16][12][4][16][64]  @ 393216
//   Sp   [16][12][4][16]      @ 1179648  (total fp32: 1191936)
// ws layout, ushort (wsh = wsf + 1191936):
//   k1b  [16][192][64]  @ 0
//   k2b  [16][192][64]  @ 196608
//   v1t  [16][64][192]  @ 393216   (columns PERMUTED within 32-chunks)
//   xh   [384][512]     @ 589824      xl @ 786432
//   Wth  [2560][512]    @ 983040      Wtl @ 2293760   (W_in^T, k-major)
//   Woth [512][512]     @ 3604480     Wotl @ 3866624  (W_out^T, k-major)
//   oh   [384][512]     @ 4128768     ol  @ 4325376   (normalized out)

#define XH_OFF   589824
#define XL_OFF   786432
#define WTH_OFF  983040
#define WTL_OFF  2293760
#define WOTH_OFF 3604480
#define WOTL_OFF 3866624
#define OH_OFF   4128768
#define OL_OFF   4325376

// V1 column permutation within a 32-chunk: position p' for j-offset w5:
//   p' = ((w5>>2)&3)<<3 | (w5&3)<<1 | ((w5>>4)&1)
__device__ __forceinline__ int v1perm(int t) {
  return (t & ~31) | (((t >> 2) & 3) << 3) | ((t & 3) << 1) | ((t >> 4) & 1);
}

// ------------------------------ Phase 0: prep ------------------------------
// grid 864: [0,640) W_in transpose+split (64n x 32k tiles), [640,768) W_out,
// [768,864) x hi/lo split. W goes through LDS so global writes are dense.
__global__ __launch_bounds__(256) void prep_kernel(
    const float* __restrict__ x, const float* __restrict__ Win,
    const float* __restrict__ Wout, unsigned short* __restrict__ wsh) {
  __shared__ float tile[32 * 65];
  const int bi = blockIdx.x, t = threadIdx.x;
  if (bi < 768) {
    const float* W; unsigned short *Th, *Tl; int R, n0, k0;
    if (bi < 640) {
      W = Win; Th = wsh + WTH_OFF; Tl = wsh + WTL_OFF; R = 2560;
      n0 = (bi % 40) << 6; k0 = (bi / 40) << 5;
    } else {
      const int idx = bi - 640;
      W = Wout; Th = wsh + WOTH_OFF; Tl = wsh + WOTL_OFF; R = 512;
      n0 = (idx & 7) << 6; k0 = (idx >> 3) << 5;
    }
    // phase 1: coalesced reads -> LDS [k][n] (pad 65)
    const int n = t & 63, kq = (t >> 6) * 8;
#pragma unroll
    for (int j = 0; j < 8; ++j)
      tile[(kq + j) * 65 + n] = W[(k0 + kq + j) * R + n0 + n];
    __syncthreads();
    // phase 2: k-contig hi/lo writes (dense 64B lines)
    const int n2 = t >> 2, ks = (t & 3) * 8;
    union { uint4 u; unsigned short us[8]; } ph, pl;
#pragma unroll
    for (int j = 0; j < 8; ++j) {
      const float v = tile[(ks + j) * 65 + n2];
      const unsigned short h = f2bf(v);
      ph.us[j] = h;
      pl.us[j] = f2bf(v - bf2f(h));
    }
    *(uint4*)(Th + (n0 + n2) * 512 + k0 + ks) = ph.u;
    *(uint4*)(Tl + (n0 + n2) * 512 + k0 + ks) = pl.u;
  } else {
    const int flat = ((bi - 768) * 256 + t) * 8;
    const v4f v0 = *(const v4f*)(x + flat);
    const v4f v1 = *(const v4f*)(x + flat + 4);
    union { uint4 u; unsigned short us[8]; } ph, pl;
#pragma unroll
    for (int j = 0; j < 4; ++j) {
      unsigned short h = f2bf(v0[j]);
      ph.us[j] = h; pl.us[j] = f2bf(v0[j] - bf2f(h));
      h = f2bf(v1[j]);
      ph.us[4 + j] = h; pl.us[4 + j] = f2bf(v1[j] - bf2f(h));
    }
    *(uint4*)(wsh + XH_OFF + flat) = ph.u;
    *(uint4*)(wsh + XL_OFF + flat) = pl.u;
  }
}

// ------------------------------ Phase 1: proj (bf16x3 MFMA) ----------------
// grid 960 x 64thr: 1 wave/block, 32x32 C-tile, prefetch depth 2.
__global__ __launch_bounds__(64) void proj_kernel(
    const unsigned short* __restrict__ wsh, const float* __restrict__ bin,
    float* __restrict__ wsf, unsigned short* __restrict__ wshd) {
  const int lane = threadIdx.x;
  const int c = lane & 15, q = lane >> 4;
  const int bm = blockIdx.x % 12, bn = blockIdx.x / 12;

  const unsigned short* base[8];
  base[0] = wsh + XH_OFF + (bm * 32 + c) * 512 + (q << 3);
  base[1] = base[0] + 16 * 512;
  base[2] = wsh + XL_OFF + (bm * 32 + c) * 512 + (q << 3);
  base[3] = base[2] + 16 * 512;
  base[4] = wsh + WTH_OFF + (bn * 32 + c) * 512 + (q << 3);
  base[5] = base[4] + 16 * 512;
  base[6] = wsh + WTL_OFF + (bn * 32 + c) * 512 + (q << 3);
  base[7] = base[6] + 16 * 512;

  const v4f z = {0.f, 0.f, 0.f, 0.f};
  v4f a00 = z, a01 = z, a10 = z, a11 = z;

  v8s cur[8], nxt[8];
#pragma unroll
  for (int i = 0; i < 8; ++i) cur[i] = *(const v8s*)(base[i]);
#pragma unroll
  for (int i = 0; i < 8; ++i) nxt[i] = *(const v8s*)(base[i] + 32);

#pragma unroll 1
  for (int ks = 0; ks < 16; ++ks) {
    v8s nx2[8];
    if (ks < 14) {
      const int o = (ks + 2) * 32;
#pragma unroll
      for (int i = 0; i < 8; ++i) nx2[i] = *(const v8s*)(base[i] + o);
    }
    // Ah0,Ah1,Al0,Al1 = cur[0..3]; Bh0,Bh1,Bl0,Bl1 = cur[4..7]
    a00 = MFMA32(cur[2], cur[4], a00); a00 = MFMA32(cur[0], cur[6], a00); a00 = MFMA32(cur[0], cur[4], a00);
    a01 = MFMA32(cur[2], cur[5], a01); a01 = MFMA32(cur[0], cur[7], a01); a01 = MFMA32(cur[0], cur[5], a01);
    a10 = MFMA32(cur[3], cur[4], a10); a10 = MFMA32(cur[1], cur[6], a10); a10 = MFMA32(cur[1], cur[4], a10);
    a11 = MFMA32(cur[3], cur[5], a11); a11 = MFMA32(cur[1], cur[7], a11); a11 = MFMA32(cur[1], cur[5], a11);
#pragma unroll
    for (int i = 0; i < 8; ++i) { cur[i] = nxt[i]; nxt[i] = nx2[i]; }
  }

  v4f accs[2][2] = {{a00, a01}, {a10, a11}};
#pragma unroll
  for (int mt = 0; mt < 2; ++mt) {
#pragma unroll
    for (int nt = 0; nt < 2; ++nt) {
      const int n = bn * 32 + nt * 16 + c;
      const int which = n >> 9, cc = n & 511, h = cc >> 6, d = cc & 63;
      const float bv = bin[n];
#pragma unroll
      for (int r = 0; r < 4; ++r) {
        const int m = bm * 32 + mt * 16 + (q << 2) + r;
        const int b = (m >= 192) ? 1 : 0;
        const int tt = m - (b ? 192 : 0);
        const int bh = b * 8 + h;
        const float val = accs[mt][nt][r] + bv;
        const int rm = ((bh * 192 + tt) << 6) + d;
        if (which == 0)      wsf[rm] = val * QSCALE;
        else if (which == 1) wshd[rm] = f2bf(val);
        else if (which == 2) wshd[393216 + ((bh << 6) + d) * 192 + v1perm(tt)] = f2bf(val);
        else if (which == 3) wshd[196608 + rm] = f2bf(val);
        else wsf[196608 + ((bh * 192 + tt) * 16 + (d & 15)) * 4 + (d >> 4)] = val;
      }
    }
  }
}

// ------------------------------ Phase 2: attention -------------------------
// grid = 16(bh)*12(i)*4(ksplit) = 768 blocks, 256 thr (4 waves).
// R5: LDS = V1s + Pw only (52224 B) => 3 blocks/CU, whole grid resident.
// k2 rows read direct from global (broadcast, L1/L2-hit) with depth-1
// register prefetch; v2 likewise prefetched.
__global__ __launch_bounds__(256, 3) void attn_kernel(
    const float* __restrict__ wsf, const unsigned short* __restrict__ wsh,
    float* __restrict__ accp, float* __restrict__ Sp) {
  __shared__ char smem[52224];
  unsigned short* V1s = (unsigned short*)smem;            // [64][200]

  const int tid  = threadIdx.x;
  const int wv   = tid >> 6;
  const int lane = tid & 63;
  const int c    = lane & 15;
  const int quad = lane >> 4;

  const int bb = blockIdx.x;
  const int kb = bb & 3;
  const int it = (bb >> 2) % 12;
  const int bh = bb / 48;

  const unsigned short* k1g = wsh + bh * 192 * 64;
  const unsigned short* v1g = wsh + 393216 + bh * 64 * 192;
  const unsigned short* k2g = wsh + 196608 + bh * 192 * 64;
  const float*          v2g = wsf + 196608 + bh * 12288;   // [192][16][4]

  const int kloc0 = wv * 12;

  // per-wave global pointers for this wave's 12 k2 rows / v2 rows
  const unsigned short* k2r = k2g + ((kb * 48 + kloc0) << 6) + (quad << 3);
  const float*          v2r = v2g + (((kb * 48 + kloc0) << 4) + c) * 4;

  union U4 { uint4 u4; unsigned short us[8]; };
  union AF { v8s v; unsigned u[4]; };

  // pair-0 k2/v2 loads issued early (global; overlap with staging below)
  U4 klA, khA, klB, khB;
  v4f v2A, v2B;
  klA.u4 = *(const uint4*)(k2r);
  khA.u4 = *(const uint4*)(k2r + 32);
  klB.u4 = *(const uint4*)(k2r + 64);
  khB.u4 = *(const uint4*)(k2r + 96);
  v2A = *(const v4f*)(v2r);
  v2B = *(const v4f*)(v2r + 64);

  // stage V1^T (permuted cols, stride 200)
  for (int idx = tid; idx < 1536; idx += 256) {
    const int r = idx / 24, c8 = (idx % 24) * 8;
    *(uint4*)(V1s + r * 200 + c8) = *(const uint4*)(v1g + r * 192 + c8);
  }

  // K1 B-frags resident in VGPRs: frag[jt][h] = K1[jt*16+c][h*32 + quad*8 ..+8]
  v8s k1f[12][2];
#pragma unroll
  for (int jt = 0; jt < 12; ++jt) {
    const unsigned short* kp = k1g + ((jt * 16 + c) << 6) + (quad << 3);
    k1f[jt][0] = *(const v8s*)(kp);
    k1f[jt][1] = *(const v8s*)(kp + 32);
  }

  // q rows (fp32, pre-scaled): i = it*16+c, d = quad*8+e (+32)
  const float* qg = wsf + ((bh * 192 + it * 16 + c) << 6) + (quad << 3);
  float q0[8], q1[8];
  {
    v4f qa = *(const v4f*)(qg), qb = *(const v4f*)(qg + 4);
    v4f qc = *(const v4f*)(qg + 32), qd = *(const v4f*)(qg + 36);
#pragma unroll
    for (int e = 0; e < 4; ++e) {
      q0[e] = qa[e]; q0[4 + e] = qb[e];
      q1[e] = qc[e]; q1[4 + e] = qd[e];
    }
  }
  __syncthreads();   // staging done; no barriers until epilogue

  unsigned* Pw = (unsigned*)(smem + 25600) + wv * 1664;  // [2 kk][16 i][52 dw]
  const v4f z = {0.f, 0.f, 0.f, 0.f};
  v4f acc[4] = {z, z, z, z};
  v4f oSA = z, oSB = z;
  const short one = (short)0x3F80;
  const v8s ones = {one, one, one, one, one, one, one, one};

#pragma unroll 1
  for (int p = 0; p < 6; ++p) {
    // depth-1 prefetch of next pair's k2/v2 (global, L1/L2-resident)
    U4 nklA, nkhA, nklB, nkhB;
    v4f nv2A, nv2B;
    if (p < 5) {
      const unsigned short* nk = k2r + (p + 1) * 128;
      nklA.u4 = *(const uint4*)(nk);
      nkhA.u4 = *(const uint4*)(nk + 32);
      nklB.u4 = *(const uint4*)(nk + 64);
      nkhB.u4 = *(const uint4*)(nk + 96);
      const float* nv = v2r + (p + 1) * 128;
      nv2A = *(const v4f*)(nv);
      nv2B = *(const v4f*)(nv + 64);
    }

    AF af[2][2];  // [kk][half]
#pragma unroll
    for (int e = 0; e < 4; ++e) {
      af[0][0].u[e] = pack_bf16(q0[2*e] * bf2f(klA.us[2*e]), q0[2*e+1] * bf2f(klA.us[2*e+1]));
      af[0][1].u[e] = pack_bf16(q1[2*e] * bf2f(khA.us[2*e]), q1[2*e+1] * bf2f(khA.us[2*e+1]));
      af[1][0].u[e] = pack_bf16(q0[2*e] * bf2f(klB.us[2*e]), q0[2*e+1] * bf2f(klB.us[2*e+1]));
      af[1][1].u[e] = pack_bf16(q1[2*e] * bf2f(khB.us[2*e]), q1[2*e+1] * bf2f(khB.us[2*e+1]));
    }

    v4f oA[4] = {z, z, z, z}, oB[4] = {z, z, z, z};

#pragma unroll
    for (int h = 0; h < 2; ++h) {
      // logits + exp + packed P-writes, kstep A then B
#pragma unroll
      for (int kk = 0; kk < 2; ++kk) {
        v4f C[6];
#pragma unroll
        for (int jj = 0; jj < 6; ++jj) {
          const int jt = h * 6 + jj;
          v4f t0 = MFMA32(af[kk][0].v, k1f[jt][0], z);
          C[jj] = MFMA32(af[kk][1].v, k1f[jt][1], t0);
        }
#pragma unroll
        for (int jj = 0; jj < 6; ++jj)
#pragma unroll
          for (int r = 0; r < 4; ++r) C[jj][r] = EXP2F(C[jj][r]);
#pragma unroll
        for (int m = 0; m < 3; ++m)
#pragma unroll
          for (int r = 0; r < 4; ++r)
            Pw[kk * 832 + ((quad << 2) + r) * 52 + m * 16 + c] =
                pack_bf16(C[2*m][r], C[2*m+1][r]);
      }
      // PV over the 96 j just produced; V1 frags shared by A and B
#pragma unroll
      for (int m = 0; m < 3; ++m) {
        const v8s apA = *(const v8s*)(Pw + c * 52 + m * 16 + (quad << 2));
        const v8s apB = *(const v8s*)(Pw + 832 + c * 52 + m * 16 + (quad << 2));
        oSA = MFMA32(apA, ones, oSA);
        oSB = MFMA32(apB, ones, oSB);
        const int vcol = (h * 3 + m) * 32 + (quad << 3);
#pragma unroll
        for (int t = 0; t < 4; ++t) {
          const v8s vf = *(const v8s*)(V1s + (c + 16 * t) * 200 + vcol);
          oA[t] = MFMA32(apA, vf, oA[t]);
          oB[t] = MFMA32(apB, vf, oB[t]);
        }
      }
    }
#pragma unroll
    for (int t = 0; t < 4; ++t) acc[t] += oA[t] * v2A[t] + oB[t] * v2B[t];

    klA = nklA; khA = nkhA; klB = nklB; khB = nkhB;
    v2A = nv2A; v2B = nv2B;
  }

  __syncthreads();  // reuse smem for cross-wave reduction
  float* redA = (float*)smem;              // [4][16][64]
  float* redS = (float*)smem + 4096;       // [4][16]

  if (c == 0) {
    float* rs = redS + wv * 16 + (quad << 2);
#pragma unroll
    for (int r = 0; r < 4; ++r) rs[r] = oSA[r] + oSB[r];
  }
#pragma unroll
  for (int r = 0; r < 4; ++r) {
    float* rr = redA + wv * 1024 + (((quad << 2) + r) << 6) + c;
    rr[0] = acc[0][r]; rr[16] = acc[1][r]; rr[32] = acc[2][r]; rr[48] = acc[3][r];
  }
  __syncthreads();

  const int pbase = (bh * 12 + it) * 4 + kb;
  float* ap_out = accp + pbase * 1024;
  for (int idx = tid; idx < 1024; idx += 256)
    ap_out[idx] = redA[idx] + redA[1024 + idx] + redA[2048 + idx] + redA[3072 + idx];
  if (tid < 16)
    Sp[pbase * 16 + tid] = redS[tid] + redS[16 + tid] + redS[32 + tid] + redS[48 + tid];
}

// ------------------------------ Phase 2.5: normalize -----------------------
__global__ __launch_bounds__(256) void norm_kernel(
    const float* __restrict__ accp, const float* __restrict__ Sp,
    unsigned short* __restrict__ wsh) {
  const int flat = blockIdx.x * 2048 + threadIdx.x * 8;
  const int m = flat >> 9, cc = flat & 511;
  const int b = (m >= 192) ? 1 : 0;
  const int tt = m - (b ? 192 : 0);
  const int h = cc >> 6, d0 = cc & 63;
  const int bh = b * 8 + h, it = tt >> 4, i = tt & 15;
  const int pb = (bh * 12 + it) * 4;
  const float* ap = accp + pb * 1024 + (i << 6) + d0;
  v4f a0 = *(const v4f*)(ap), a1 = *(const v4f*)(ap + 4);
  float Sv = Sp[pb * 16 + i];
#pragma unroll
  for (int kb = 1; kb < 4; ++kb) {
    a0 += *(const v4f*)(ap + kb * 1024);
    a1 += *(const v4f*)(ap + kb * 1024 + 4);
    Sv += Sp[(pb + kb) * 16 + i];
  }
  const float inv = 1.0f / Sv;
  union { uint4 u; unsigned short us[8]; } ph, pl;
#pragma unroll
  for (int j = 0; j < 4; ++j) {
    float v = a0[j] * inv;
    unsigned short hh = f2bf(v);
    ph.us[j] = hh; pl.us[j] = f2bf(v - bf2f(hh));
    v = a1[j] * inv;
    hh = f2bf(v);
    ph.us[4 + j] = hh; pl.us[4 + j] = f2bf(v - bf2f(hh));
  }
  *(uint4*)(wsh + OH_OFF + flat) = ph.u;
  *(uint4*)(wsh + OL_OFF + flat) = pl.u;
}

// ------------------------------ Phase 3: out GEMM (bf16x3 MFMA) ------------
// grid 192 x 64thr: M=384 (12), N=512 (16), K=512, prefetch depth 2.
__global__ __launch_bounds__(64) void outp_kernel(
    const unsigned short* __restrict__ wsh, const float* __restrict__ bout,
    float* __restrict__ y) {
  const int lane = threadIdx.x;
  const int c = lane & 15, q = lane >> 4;
  const int bm = blockIdx.x % 12, bn = blockIdx.x / 12;

  const unsigned short* base[8];
  base[0] = wsh + OH_OFF + (bm * 32 + c) * 512 + (q << 3);
  base[1] = base[0] + 16 * 512;
  base[2] = wsh + OL_OFF + (bm * 32 + c) * 512 + (q << 3);
  base[3] = base[2] + 16 * 512;
  base[4] = wsh + WOTH_OFF + (bn * 32 + c) * 512 + (q << 3);
  base[5] = base[4] + 16 * 512;
  base[6] = wsh + WOTL_OFF + (bn * 32 + c) * 512 + (q << 3);
  base[7] = base[6] + 16 * 512;

  const v4f z = {0.f, 0.f, 0.f, 0.f};
  v4f a00 = z, a01 = z, a10 = z, a11 = z;

  v8s cur[8], nxt[8];
#pragma unroll
  for (int i = 0; i < 8; ++i) cur[i] = *(const v8s*)(base[i]);
#pragma unroll
  for (int i = 0; i < 8; ++i) nxt[i] = *(const v8s*)(base[i] + 32);

#pragma unroll 1
  for (int ks = 0; ks < 16; ++ks) {
    v8s nx2[8];
    if (ks < 14) {
      const int o = (ks + 2) * 32;
#pragma unroll
      for (int i = 0; i < 8; ++i) nx2[i] = *(const v8s*)(base[i] + o);
    }
    a00 = MFMA32(cur[2], cur[4], a00); a00 = MFMA32(cur[0], cur[6], a00); a00 = MFMA32(cur[0], cur[4], a00);
    a01 = MFMA32(cur[2], cur[5], a01); a01 = MFMA32(cur[0], cur[7], a01); a01 = MFMA32(cur[0], cur[5], a01);
    a10 = MFMA32(cur[3], cur[4], a10); a10 = MFMA32(cur[1], cur[6], a10); a10 = MFMA32(cur[1], cur[4], a10);
    a11 = MFMA32(cur[3], cur[5], a11); a11 = MFMA32(cur[1], cur[7], a11); a11 = MFMA32(cur[1], cur[5], a11);
#pragma unroll
    for (int i = 0; i < 8; ++i) { cur[i] = nxt[i]; nxt[i] = nx2[i]; }
  }

  v4f accs[2][2] = {{a00, a01}, {a10, a11}};
#pragma unroll
  for (int mt = 0; mt < 2; ++mt) {
#pragma unroll
    for (int nt = 0; nt < 2; ++nt) {
      const int n = bn * 32 + nt * 16 + c;
      const float bv = bout[n];
#pragma unroll
      for (int r = 0; r < 4; ++r) {
        const int m = bm * 32 + mt * 16 + (q << 2) + r;
        y[m * 512 + n] = accs[mt][nt][r] + bv;
      }
    }
  }
}

// ------------------------------ launcher -----------------------------------
extern "C" void kernel_launch(void* const* d_in, const int* in_sizes, int n_in,
                              void* d_out, int out_size, void* d_ws, size_t ws_size,
                              hipStream_t stream) {
  const float* x    = (const float*)d_in[0];
  const float* Win  = (const float*)d_in[1];
  const float* bin  = (const float*)d_in[2];
  const float* Wout = (const float*)d_in[3];
  const float* bout = (const float*)d_in[4];

  float* wsf = (float*)d_ws;
  unsigned short* wsh = (unsigned short*)(wsf + 1191936);
  float* accp = wsf + 393216;
  float* Sp   = wsf + 1179648;

  prep_kernel<<<dim3(864), 256, 0, stream>>>(x, Win, Wout, wsh);
  proj_kernel<<<dim3(960), 64, 0, stream>>>(wsh, bin, wsf, wsh);
  attn_kernel<<<dim3(768), 256, 0, stream>>>(wsf, wsh, accp, Sp);
  norm_kernel<<<dim3(96), 256, 0, stream>>>(accp, Sp, wsh);
  outp_kernel<<<dim3(192), 64, 0, stream>>>(wsh, bout, (float*)d_out);
}

// Round 2
// 189.066 us; speedup vs baseline: 1.1061x; 1.1061x over previous
//
#include <hip/hip_runtime.h>
#include <hip/hip_bf16.h>

// ---------------------------------------------------------------------------
// TwoSimplicialAttention  (B=2, T=192, C=512, H=8, D=64)
// R6: R4 structure restored (no k2/v2 register prefetch -- R5's +48 persistent
//     VGPRs caused catastrophic spills: 260MB fetch / 181MB write scratch).
//     Occupancy fix kept: K2s LDS buffer dropped, k2 read direct from global
//     in-loop (transient regs, same live ranges as R4's LDS reads; broadcast,
//     L1/L2-hit). LDS 58368 -> 52224 => 3 blocks/CU, grid 768 fully resident.
// ---------------------------------------------------------------------------

typedef float  v4f __attribute__((ext_vector_type(4)));
typedef short  v8s __attribute__((ext_vector_type(8)));

__device__ __forceinline__ unsigned short f2bf(float f) {
  unsigned u = __float_as_uint(f);
  u += 0x7fffu + ((u >> 16) & 1u);       // RNE
  return (unsigned short)(u >> 16);
}
__device__ __forceinline__ float bf2f(unsigned short b) {
  return __uint_as_float(((unsigned)b) << 16);
}
__device__ __forceinline__ unsigned pack_bf16(float lo, float hi) {
  __hip_bfloat162 t = __float22bfloat162_rn(float2{lo, hi});
  union { __hip_bfloat162 b; unsigned u; } cv;
  cv.b = t;
  return cv.u;
}

#if __has_builtin(__builtin_amdgcn_exp2f)
#define EXP2F(x) __builtin_amdgcn_exp2f(x)
#else
#define EXP2F(x) exp2f(x)
#endif

#define MFMA32(a, b, c) __builtin_amdgcn_mfma_f32_16x16x32_bf16((a), (b), (c), 0, 0, 0)

// q scale = D^-0.5 * log2(e)
#define QSCALE 0.18033688011112042f

// ws layout, floats (wsf):
//   qs   [16][192][64]        @ 0        (q * 0.125*log2e, fp32)
//   v2p  [16][192][16][4]     @ 196608   ([.][k][c][r] = v2[d=c+16r], fp32)
//   accp [16][12][4][16][64]  @ 393216
//   Sp   [16][12][4][16]      @ 1179648  (total fp32: 1191936)
// ws layout, ushort (wsh = wsf + 1191936):
//   k1b  [16][192][64]  @ 0
//   k2b  [16][192][64]  @ 196608
//   v1t  [16][64][192]  @ 393216   (columns PERMUTED within 32-chunks)
//   xh   [384][512]     @ 589824      xl @ 786432
//   Wth  [2560][512]    @ 983040      Wtl @ 2293760   (W_in^T, k-major)
//   Woth [512][512]     @ 3604480     Wotl @ 3866624  (W_out^T, k-major)
//   oh   [384][512]     @ 4128768     ol  @ 4325376   (normalized out)

#define XH_OFF   589824
#define XL_OFF   786432
#define WTH_OFF  983040
#define WTL_OFF  2293760
#define WOTH_OFF 3604480
#define WOTL_OFF 3866624
#define OH_OFF   4128768
#define OL_OFF   4325376

// V1 column permutation within a 32-chunk: position p' for j-offset w5:
//   p' = ((w5>>2)&3)<<3 | (w5&3)<<1 | ((w5>>4)&1)
__device__ __forceinline__ int v1perm(int t) {
  return (t & ~31) | (((t >> 2) & 3) << 3) | ((t & 3) << 1) | ((t >> 4) & 1);
}

// ------------------------------ Phase 0: prep ------------------------------
// grid 864: [0,640) W_in transpose+split (64n x 32k tiles), [640,768) W_out,
// [768,864) x hi/lo split. W goes through LDS so global writes are dense.
__global__ __launch_bounds__(256) void prep_kernel(
    const float* __restrict__ x, const float* __restrict__ Win,
    const float* __restrict__ Wout, unsigned short* __restrict__ wsh) {
  __shared__ float tile[32 * 65];
  const int bi = blockIdx.x, t = threadIdx.x;
  if (bi < 768) {
    const float* W; unsigned short *Th, *Tl; int R, n0, k0;
    if (bi < 640) {
      W = Win; Th = wsh + WTH_OFF; Tl = wsh + WTL_OFF; R = 2560;
      n0 = (bi % 40) << 6; k0 = (bi / 40) << 5;
    } else {
      const int idx = bi - 640;
      W = Wout; Th = wsh + WOTH_OFF; Tl = wsh + WOTL_OFF; R = 512;
      n0 = (idx & 7) << 6; k0 = (idx >> 3) << 5;
    }
    // phase 1: coalesced reads -> LDS [k][n] (pad 65)
    const int n = t & 63, kq = (t >> 6) * 8;
#pragma unroll
    for (int j = 0; j < 8; ++j)
      tile[(kq + j) * 65 + n] = W[(k0 + kq + j) * R + n0 + n];
    __syncthreads();
    // phase 2: k-contig hi/lo writes (dense 64B lines)
    const int n2 = t >> 2, ks = (t & 3) * 8;
    union { uint4 u; unsigned short us[8]; } ph, pl;
#pragma unroll
    for (int j = 0; j < 8; ++j) {
      const float v = tile[(ks + j) * 65 + n2];
      const unsigned short h = f2bf(v);
      ph.us[j] = h;
      pl.us[j] = f2bf(v - bf2f(h));
    }
    *(uint4*)(Th + (n0 + n2) * 512 + k0 + ks) = ph.u;
    *(uint4*)(Tl + (n0 + n2) * 512 + k0 + ks) = pl.u;
  } else {
    const int flat = ((bi - 768) * 256 + t) * 8;
    const v4f v0 = *(const v4f*)(x + flat);
    const v4f v1 = *(const v4f*)(x + flat + 4);
    union { uint4 u; unsigned short us[8]; } ph, pl;
#pragma unroll
    for (int j = 0; j < 4; ++j) {
      unsigned short h = f2bf(v0[j]);
      ph.us[j] = h; pl.us[j] = f2bf(v0[j] - bf2f(h));
      h = f2bf(v1[j]);
      ph.us[4 + j] = h; pl.us[4 + j] = f2bf(v1[j] - bf2f(h));
    }
    *(uint4*)(wsh + XH_OFF + flat) = ph.u;
    *(uint4*)(wsh + XL_OFF + flat) = pl.u;
  }
}

// ------------------------------ Phase 1: proj (bf16x3 MFMA) ----------------
// grid 960 x 64thr: 1 wave/block, 32x32 C-tile, prefetch depth 2.
__global__ __launch_bounds__(64) void proj_kernel(
    const unsigned short* __restrict__ wsh, const float* __restrict__ bin,
    float* __restrict__ wsf, unsigned short* __restrict__ wshd) {
  const int lane = threadIdx.x;
  const int c = lane & 15, q = lane >> 4;
  const int bm = blockIdx.x % 12, bn = blockIdx.x / 12;

  const unsigned short* base[8];
  base[0] = wsh + XH_OFF + (bm * 32 + c) * 512 + (q << 3);
  base[1] = base[0] + 16 * 512;
  base[2] = wsh + XL_OFF + (bm * 32 + c) * 512 + (q << 3);
  base[3] = base[2] + 16 * 512;
  base[4] = wsh + WTH_OFF + (bn * 32 + c) * 512 + (q << 3);
  base[5] = base[4] + 16 * 512;
  base[6] = wsh + WTL_OFF + (bn * 32 + c) * 512 + (q << 3);
  base[7] = base[6] + 16 * 512;

  const v4f z = {0.f, 0.f, 0.f, 0.f};
  v4f a00 = z, a01 = z, a10 = z, a11 = z;

  v8s cur[8], nxt[8];
#pragma unroll
  for (int i = 0; i < 8; ++i) cur[i] = *(const v8s*)(base[i]);
#pragma unroll
  for (int i = 0; i < 8; ++i) nxt[i] = *(const v8s*)(base[i] + 32);

#pragma unroll 1
  for (int ks = 0; ks < 16; ++ks) {
    v8s nx2[8];
    if (ks < 14) {
      const int o = (ks + 2) * 32;
#pragma unroll
      for (int i = 0; i < 8; ++i) nx2[i] = *(const v8s*)(base[i] + o);
    }
    // Ah0,Ah1,Al0,Al1 = cur[0..3]; Bh0,Bh1,Bl0,Bl1 = cur[4..7]
    a00 = MFMA32(cur[2], cur[4], a00); a00 = MFMA32(cur[0], cur[6], a00); a00 = MFMA32(cur[0], cur[4], a00);
    a01 = MFMA32(cur[2], cur[5], a01); a01 = MFMA32(cur[0], cur[7], a01); a01 = MFMA32(cur[0], cur[5], a01);
    a10 = MFMA32(cur[3], cur[4], a10); a10 = MFMA32(cur[1], cur[6], a10); a10 = MFMA32(cur[1], cur[4], a10);
    a11 = MFMA32(cur[3], cur[5], a11); a11 = MFMA32(cur[1], cur[7], a11); a11 = MFMA32(cur[1], cur[5], a11);
#pragma unroll
    for (int i = 0; i < 8; ++i) { cur[i] = nxt[i]; nxt[i] = nx2[i]; }
  }

  v4f accs[2][2] = {{a00, a01}, {a10, a11}};
#pragma unroll
  for (int mt = 0; mt < 2; ++mt) {
#pragma unroll
    for (int nt = 0; nt < 2; ++nt) {
      const int n = bn * 32 + nt * 16 + c;
      const int which = n >> 9, cc = n & 511, h = cc >> 6, d = cc & 63;
      const float bv = bin[n];
#pragma unroll
      for (int r = 0; r < 4; ++r) {
        const int m = bm * 32 + mt * 16 + (q << 2) + r;
        const int b = (m >= 192) ? 1 : 0;
        const int tt = m - (b ? 192 : 0);
        const int bh = b * 8 + h;
        const float val = accs[mt][nt][r] + bv;
        const int rm = ((bh * 192 + tt) << 6) + d;
        if (which == 0)      wsf[rm] = val * QSCALE;
        else if (which == 1) wshd[rm] = f2bf(val);
        else if (which == 2) wshd[393216 + ((bh << 6) + d) * 192 + v1perm(tt)] = f2bf(val);
        else if (which == 3) wshd[196608 + rm] = f2bf(val);
        else wsf[196608 + ((bh * 192 + tt) * 16 + (d & 15)) * 4 + (d >> 4)] = val;
      }
    }
  }
}

// ------------------------------ Phase 2: attention -------------------------
// grid = 16(bh)*12(i)*4(ksplit) = 768 blocks, 256 thr (4 waves).
// Per wave: 6 kstep-PAIRS; per pair: batched L-MFMA/exp/pack, shared V1 frag
// reads feed both ksteps' PV. S accumulated via MFMA with ones-B.
// k2 read direct from global (transient regs, 16-lane broadcast, L2-hit).
// LDS 52224 => 3 blocks/CU; grid 768 = 3*256 fully resident, no tail pass.
__global__ __launch_bounds__(256, 3) void attn_kernel(
    const float* __restrict__ wsf, const unsigned short* __restrict__ wsh,
    float* __restrict__ accp, float* __restrict__ Sp) {
  __shared__ char smem[52224];
  unsigned short* V1s = (unsigned short*)smem;            // [64][200]

  const int tid  = threadIdx.x;
  const int wv   = tid >> 6;
  const int lane = tid & 63;
  const int c    = lane & 15;
  const int quad = lane >> 4;

  const int bb = blockIdx.x;
  const int kb = bb & 3;
  const int it = (bb >> 2) % 12;
  const int bh = bb / 48;

  const unsigned short* k1g = wsh + bh * 192 * 64;
  const unsigned short* v1g = wsh + 393216 + bh * 64 * 192;
  const unsigned short* k2g = wsh + 196608 + bh * 192 * 64;
  const float*          v2g = wsf + 196608 + bh * 12288;   // [192][16][4]

  // stage V1^T (permuted cols, stride 200)
  for (int idx = tid; idx < 1536; idx += 256) {
    const int r = idx / 24, c8 = (idx % 24) * 8;
    *(uint4*)(V1s + r * 200 + c8) = *(const uint4*)(v1g + r * 192 + c8);
  }

  // K1 B-frags resident in VGPRs: frag[jt][h] = K1[jt*16+c][h*32 + quad*8 ..+8]
  v8s k1f[12][2];
#pragma unroll
  for (int jt = 0; jt < 12; ++jt) {
    const unsigned short* kp = k1g + ((jt * 16 + c) << 6) + (quad << 3);
    k1f[jt][0] = *(const v8s*)(kp);
    k1f[jt][1] = *(const v8s*)(kp + 32);
  }

  // q rows (fp32, pre-scaled): i = it*16+c, d = quad*8+e (+32)
  const float* qg = wsf + ((bh * 192 + it * 16 + c) << 6) + (quad << 3);
  float q0[8], q1[8];
  {
    v4f qa = *(const v4f*)(qg), qb = *(const v4f*)(qg + 4);
    v4f qc = *(const v4f*)(qg + 32), qd = *(const v4f*)(qg + 36);
#pragma unroll
    for (int e = 0; e < 4; ++e) {
      q0[e] = qa[e]; q0[4 + e] = qb[e];
      q1[e] = qc[e]; q1[4 + e] = qd[e];
    }
  }
  __syncthreads();   // staging done; no barriers until epilogue

  unsigned* Pw = (unsigned*)(smem + 25600) + wv * 1664;  // [2 kk][16 i][52 dw]
  const v4f z = {0.f, 0.f, 0.f, 0.f};
  v4f acc[4] = {z, z, z, z};
  v4f oSA = z, oSB = z;
  const short one = (short)0x3F80;
  const v8s ones = {one, one, one, one, one, one, one, one};

  const int kloc0 = wv * 12;
  // per-wave global base for this wave's k2 rows (row 0 = kb*48 + kloc0)
  const unsigned short* k2r = k2g + ((kb * 48 + kloc0) << 6) + (quad << 3);
  union U4 { uint4 u4; unsigned short us[8]; };
  union AF { v8s v; unsigned u[4]; };

#pragma unroll 1
  for (int p = 0; p < 6; ++p) {
    const int rA = kloc0 + 2 * p, rB = rA + 1;
    U4 klA, khA, klB, khB;
    klA.u4 = *(const uint4*)(k2r + p * 128);
    khA.u4 = *(const uint4*)(k2r + p * 128 + 32);
    klB.u4 = *(const uint4*)(k2r + p * 128 + 64);
    khB.u4 = *(const uint4*)(k2r + p * 128 + 96);
    const v4f v2A = *(const v4f*)(v2g + (((kb * 48 + rA) << 4) + c) * 4);
    const v4f v2B = *(const v4f*)(v2g + (((kb * 48 + rB) << 4) + c) * 4);

    AF af[2][2];  // [kk][half]
#pragma unroll
    for (int e = 0; e < 4; ++e) {
      af[0][0].u[e] = pack_bf16(q0[2*e] * bf2f(klA.us[2*e]), q0[2*e+1] * bf2f(klA.us[2*e+1]));
      af[0][1].u[e] = pack_bf16(q1[2*e] * bf2f(khA.us[2*e]), q1[2*e+1] * bf2f(khA.us[2*e+1]));
      af[1][0].u[e] = pack_bf16(q0[2*e] * bf2f(klB.us[2*e]), q0[2*e+1] * bf2f(klB.us[2*e+1]));
      af[1][1].u[e] = pack_bf16(q1[2*e] * bf2f(khB.us[2*e]), q1[2*e+1] * bf2f(khB.us[2*e+1]));
    }

    v4f oA[4] = {z, z, z, z}, oB[4] = {z, z, z, z};

#pragma unroll
    for (int h = 0; h < 2; ++h) {
      // logits + exp + packed P-writes, kstep A then B
#pragma unroll
      for (int kk = 0; kk < 2; ++kk) {
        v4f C[6];
#pragma unroll
        for (int jj = 0; jj < 6; ++jj) {
          const int jt = h * 6 + jj;
          v4f t0 = MFMA32(af[kk][0].v, k1f[jt][0], z);
          C[jj] = MFMA32(af[kk][1].v, k1f[jt][1], t0);
        }
#pragma unroll
        for (int jj = 0; jj < 6; ++jj)
#pragma unroll
          for (int r = 0; r < 4; ++r) C[jj][r] = EXP2F(C[jj][r]);
#pragma unroll
        for (int m = 0; m < 3; ++m)
#pragma unroll
          for (int r = 0; r < 4; ++r)
            Pw[kk * 832 + ((quad << 2) + r) * 52 + m * 16 + c] =
                pack_bf16(C[2*m][r], C[2*m+1][r]);
      }
      // PV over the 96 j just produced; V1 frags shared by A and B
#pragma unroll
      for (int m = 0; m < 3; ++m) {
        const v8s apA = *(const v8s*)(Pw + c * 52 + m * 16 + (quad << 2));
        const v8s apB = *(const v8s*)(Pw + 832 + c * 52 + m * 16 + (quad << 2));
        oSA = MFMA32(apA, ones, oSA);
        oSB = MFMA32(apB, ones, oSB);
        const int vcol = (h * 3 + m) * 32 + (quad << 3);
#pragma unroll
        for (int t = 0; t < 4; ++t) {
          const v8s vf = *(const v8s*)(V1s + (c + 16 * t) * 200 + vcol);
          oA[t] = MFMA32(apA, vf, oA[t]);
          oB[t] = MFMA32(apB, vf, oB[t]);
        }
      }
    }
#pragma unroll
    for (int t = 0; t < 4; ++t) acc[t] += oA[t] * v2A[t] + oB[t] * v2B[t];
  }

  __syncthreads();  // reuse smem for cross-wave reduction
  float* redA = (float*)smem;              // [4][16][64]
  float* redS = (float*)smem + 4096;       // [4][16]

  if (c == 0) {
    float* rs = redS + wv * 16 + (quad << 2);
#pragma unroll
    for (int r = 0; r < 4; ++r) rs[r] = oSA[r] + oSB[r];
  }
#pragma unroll
  for (int r = 0; r < 4; ++r) {
    float* rr = redA + wv * 1024 + (((quad << 2) + r) << 6) + c;
    rr[0] = acc[0][r]; rr[16] = acc[1][r]; rr[32] = acc[2][r]; rr[48] = acc[3][r];
  }
  __syncthreads();

  const int pbase = (bh * 12 + it) * 4 + kb;
  float* ap_out = accp + pbase * 1024;
  for (int idx = tid; idx < 1024; idx += 256)
    ap_out[idx] = redA[idx] + redA[1024 + idx] + redA[2048 + idx] + redA[3072 + idx];
  if (tid < 16)
    Sp[pbase * 16 + tid] = redS[tid] + redS[16 + tid] + redS[32 + tid] + redS[48 + tid];
}

// ------------------------------ Phase 2.5: normalize -----------------------
__global__ __launch_bounds__(256) void norm_kernel(
    const float* __restrict__ accp, const float* __restrict__ Sp,
    unsigned short* __restrict__ wsh) {
  const int flat = blockIdx.x * 2048 + threadIdx.x * 8;
  const int m = flat >> 9, cc = flat & 511;
  const int b = (m >= 192) ? 1 : 0;
  const int tt = m - (b ? 192 : 0);
  const int h = cc >> 6, d0 = cc & 63;
  const int bh = b * 8 + h, it = tt >> 4, i = tt & 15;
  const int pb = (bh * 12 + it) * 4;
  const float* ap = accp + pb * 1024 + (i << 6) + d0;
  v4f a0 = *(const v4f*)(ap), a1 = *(const v4f*)(ap + 4);
  float Sv = Sp[pb * 16 + i];
#pragma unroll
  for (int kb = 1; kb < 4; ++kb) {
    a0 += *(const v4f*)(ap + kb * 1024);
    a1 += *(const v4f*)(ap + kb * 1024 + 4);
    Sv += Sp[(pb + kb) * 16 + i];
  }
  const float inv = 1.0f / Sv;
  union { uint4 u; unsigned short us[8]; } ph, pl;
#pragma unroll
  for (int j = 0; j < 4; ++j) {
    float v = a0[j] * inv;
    unsigned short hh = f2bf(v);
    ph.us[j] = hh; pl.us[j] = f2bf(v - bf2f(hh));
    v = a1[j] * inv;
    hh = f2bf(v);
    ph.us[4 + j] = hh; pl.us[4 + j] = f2bf(v - bf2f(hh));
  }
  *(uint4*)(wsh + OH_OFF + flat) = ph.u;
  *(uint4*)(wsh + OL_OFF + flat) = pl.u;
}

// ------------------------------ Phase 3: out GEMM (bf16x3 MFMA) ------------
// grid 192 x 64thr: M=384 (12), N=512 (16), K=512, prefetch depth 2.
__global__ __launch_bounds__(64) void outp_kernel(
    const unsigned short* __restrict__ wsh, const float* __restrict__ bout,
    float* __restrict__ y) {
  const int lane = threadIdx.x;
  const int c = lane & 15, q = lane >> 4;
  const int bm = blockIdx.x % 12, bn = blockIdx.x / 12;

  const unsigned short* base[8];
  base[0] = wsh + OH_OFF + (bm * 32 + c) * 512 + (q << 3);
  base[1] = base[0] + 16 * 512;
  base[2] = wsh + OL_OFF + (bm * 32 + c) * 512 + (q << 3);
  base[3] = base[2] + 16 * 512;
  base[4] = wsh + WOTH_OFF + (bn * 32 + c) * 512 + (q << 3);
  base[5] = base[4] + 16 * 512;
  base[6] = wsh + WOTL_OFF + (bn * 32 + c) * 512 + (q << 3);
  base[7] = base[6] + 16 * 512;

  const v4f z = {0.f, 0.f, 0.f, 0.f};
  v4f a00 = z, a01 = z, a10 = z, a11 = z;

  v8s cur[8], nxt[8];
#pragma unroll
  for (int i = 0; i < 8; ++i) cur[i] = *(const v8s*)(base[i]);
#pragma unroll
  for (int i = 0; i < 8; ++i) nxt[i] = *(const v8s*)(base[i] + 32);

#pragma unroll 1
  for (int ks = 0; ks < 16; ++ks) {
    v8s nx2[8];
    if (ks < 14) {
      const int o = (ks + 2) * 32;
#pragma unroll
      for (int i = 0; i < 8; ++i) nx2[i] = *(const v8s*)(base[i] + o);
    }
    a00 = MFMA32(cur[2], cur[4], a00); a00 = MFMA32(cur[0], cur[6], a00); a00 = MFMA32(cur[0], cur[4], a00);
    a01 = MFMA32(cur[2], cur[5], a01); a01 = MFMA32(cur[0], cur[7], a01); a01 = MFMA32(cur[0], cur[5], a01);
    a10 = MFMA32(cur[3], cur[4], a10); a10 = MFMA32(cur[1], cur[6], a10); a10 = MFMA32(cur[1], cur[4], a10);
    a11 = MFMA32(cur[3], cur[5], a11); a11 = MFMA32(cur[1], cur[7], a11); a11 = MFMA32(cur[1], cur[5], a11);
#pragma unroll
    for (int i = 0; i < 8; ++i) { cur[i] = nxt[i]; nxt[i] = nx2[i]; }
  }

  v4f accs[2][2] = {{a00, a01}, {a10, a11}};
#pragma unroll
  for (int mt = 0; mt < 2; ++mt) {
#pragma unroll
    for (int nt = 0; nt < 2; ++nt) {
      const int n = bn * 32 + nt * 16 + c;
      const float bv = bout[n];
#pragma unroll
      for (int r = 0; r < 4; ++r) {
        const int m = bm * 32 + mt * 16 + (q << 2) + r;
        y[m * 512 + n] = accs[mt][nt][r] + bv;
      }
    }
  }
}

// ------------------------------ launcher -----------------------------------
extern "C" void kernel_launch(void* const* d_in, const int* in_sizes, int n_in,
                              void* d_out, int out_size, void* d_ws, size_t ws_size,
                              hipStream_t stream) {
  const float* x    = (const float*)d_in[0];
  const float* Win  = (const float*)d_in[1];
  const float* bin  = (const float*)d_in[2];
  const float* Wout = (const float*)d_in[3];
  const float* bout = (const float*)d_in[4];

  float* wsf = (float*)d_ws;
  unsigned short* wsh = (unsigned short*)(wsf + 1191936);
  float* accp = wsf + 393216;
  float* Sp   = wsf + 1179648;

  prep_kernel<<<dim3(864), 256, 0, stream>>>(x, Win, Wout, wsh);
  proj_kernel<<<dim3(960), 64, 0, stream>>>(wsh, bin, wsf, wsh);
  attn_kernel<<<dim3(768), 256, 0, stream>>>(wsf, wsh, accp, Sp);
  norm_kernel<<<dim3(96), 256, 0, stream>>>(accp, Sp, wsh);
  outp_kernel<<<dim3(192), 64, 0, stream>>>(wsh, bout, (float*)d_out);
}

// Round 3
// 150.094 us; speedup vs baseline: 1.3933x; 1.2596x over previous
//
#include <hip/hip_runtime.h>
#include <hip/hip_bf16.h>

// ---------------------------------------------------------------------------
// TwoSimplicialAttention  (B=2, T=192, C=512, H=8, D=64)
// R7: R6 with launch_bounds(256,2) on attn. The (256,3) bound made hipcc cap
//     arch VGPRs at 84 (~256/3) and spill k1f (199MB fetch / 90MB write of
//     scratch traffic). With (256,2) the allocator keeps the R4-proven
//     ~120-VGPR spill-free budget; occupancy is then LDS-limited at
//     163840/52224 = 3 blocks/CU anyway => grid 768 = 3*256 fully resident.
// ---------------------------------------------------------------------------

typedef float  v4f __attribute__((ext_vector_type(4)));
typedef short  v8s __attribute__((ext_vector_type(8)));

__device__ __forceinline__ unsigned short f2bf(float f) {
  unsigned u = __float_as_uint(f);
  u += 0x7fffu + ((u >> 16) & 1u);       // RNE
  return (unsigned short)(u >> 16);
}
__device__ __forceinline__ float bf2f(unsigned short b) {
  return __uint_as_float(((unsigned)b) << 16);
}
__device__ __forceinline__ unsigned pack_bf16(float lo, float hi) {
  __hip_bfloat162 t = __float22bfloat162_rn(float2{lo, hi});
  union { __hip_bfloat162 b; unsigned u; } cv;
  cv.b = t;
  return cv.u;
}

#if __has_builtin(__builtin_amdgcn_exp2f)
#define EXP2F(x) __builtin_amdgcn_exp2f(x)
#else
#define EXP2F(x) exp2f(x)
#endif

#define MFMA32(a, b, c) __builtin_amdgcn_mfma_f32_16x16x32_bf16((a), (b), (c), 0, 0, 0)

// q scale = D^-0.5 * log2(e)
#define QSCALE 0.18033688011112042f

// ws layout, floats (wsf):
//   qs   [16][192][64]        @ 0        (q * 0.125*log2e, fp32)
//   v2p  [16][192][16][4]     @ 196608   ([.][k][c][r] = v2[d=c+16r], fp32)
//   accp [16][12][4][16][64]  @ 393216
//   Sp   [16][12][4][16]      @ 1179648  (total fp32: 1191936)
// ws layout, ushort (wsh = wsf + 1191936):
//   k1b  [16][192][64]  @ 0
//   k2b  [16][192][64]  @ 196608
//   v1t  [16][64][192]  @ 393216   (columns PERMUTED within 32-chunks)
//   xh   [384][512]     @ 589824      xl @ 786432
//   Wth  [2560][512]    @ 983040      Wtl @ 2293760   (W_in^T, k-major)
//   Woth [512][512]     @ 3604480     Wotl @ 3866624  (W_out^T, k-major)
//   oh   [384][512]     @ 4128768     ol  @ 4325376   (normalized out)

#define XH_OFF   589824
#define XL_OFF   786432
#define WTH_OFF  983040
#define WTL_OFF  2293760
#define WOTH_OFF 3604480
#define WOTL_OFF 3866624
#define OH_OFF   4128768
#define OL_OFF   4325376

// V1 column permutation within a 32-chunk: position p' for j-offset w5:
//   p' = ((w5>>2)&3)<<3 | (w5&3)<<1 | ((w5>>4)&1)
__device__ __forceinline__ int v1perm(int t) {
  return (t & ~31) | (((t >> 2) & 3) << 3) | ((t & 3) << 1) | ((t >> 4) & 1);
}

// ------------------------------ Phase 0: prep ------------------------------
// grid 864: [0,640) W_in transpose+split (64n x 32k tiles), [640,768) W_out,
// [768,864) x hi/lo split. W goes through LDS so global writes are dense.
__global__ __launch_bounds__(256) void prep_kernel(
    const float* __restrict__ x, const float* __restrict__ Win,
    const float* __restrict__ Wout, unsigned short* __restrict__ wsh) {
  __shared__ float tile[32 * 65];
  const int bi = blockIdx.x, t = threadIdx.x;
  if (bi < 768) {
    const float* W; unsigned short *Th, *Tl; int R, n0, k0;
    if (bi < 640) {
      W = Win; Th = wsh + WTH_OFF; Tl = wsh + WTL_OFF; R = 2560;
      n0 = (bi % 40) << 6; k0 = (bi / 40) << 5;
    } else {
      const int idx = bi - 640;
      W = Wout; Th = wsh + WOTH_OFF; Tl = wsh + WOTL_OFF; R = 512;
      n0 = (idx & 7) << 6; k0 = (idx >> 3) << 5;
    }
    // phase 1: coalesced reads -> LDS [k][n] (pad 65)
    const int n = t & 63, kq = (t >> 6) * 8;
#pragma unroll
    for (int j = 0; j < 8; ++j)
      tile[(kq + j) * 65 + n] = W[(k0 + kq + j) * R + n0 + n];
    __syncthreads();
    // phase 2: k-contig hi/lo writes (dense 64B lines)
    const int n2 = t >> 2, ks = (t & 3) * 8;
    union { uint4 u; unsigned short us[8]; } ph, pl;
#pragma unroll
    for (int j = 0; j < 8; ++j) {
      const float v = tile[(ks + j) * 65 + n2];
      const unsigned short h = f2bf(v);
      ph.us[j] = h;
      pl.us[j] = f2bf(v - bf2f(h));
    }
    *(uint4*)(Th + (n0 + n2) * 512 + k0 + ks) = ph.u;
    *(uint4*)(Tl + (n0 + n2) * 512 + k0 + ks) = pl.u;
  } else {
    const int flat = ((bi - 768) * 256 + t) * 8;
    const v4f v0 = *(const v4f*)(x + flat);
    const v4f v1 = *(const v4f*)(x + flat + 4);
    union { uint4 u; unsigned short us[8]; } ph, pl;
#pragma unroll
    for (int j = 0; j < 4; ++j) {
      unsigned short h = f2bf(v0[j]);
      ph.us[j] = h; pl.us[j] = f2bf(v0[j] - bf2f(h));
      h = f2bf(v1[j]);
      ph.us[4 + j] = h; pl.us[4 + j] = f2bf(v1[j] - bf2f(h));
    }
    *(uint4*)(wsh + XH_OFF + flat) = ph.u;
    *(uint4*)(wsh + XL_OFF + flat) = pl.u;
  }
}

// ------------------------------ Phase 1: proj (bf16x3 MFMA) ----------------
// grid 960 x 64thr: 1 wave/block, 32x32 C-tile, prefetch depth 2.
__global__ __launch_bounds__(64) void proj_kernel(
    const unsigned short* __restrict__ wsh, const float* __restrict__ bin,
    float* __restrict__ wsf, unsigned short* __restrict__ wshd) {
  const int lane = threadIdx.x;
  const int c = lane & 15, q = lane >> 4;
  const int bm = blockIdx.x % 12, bn = blockIdx.x / 12;

  const unsigned short* base[8];
  base[0] = wsh + XH_OFF + (bm * 32 + c) * 512 + (q << 3);
  base[1] = base[0] + 16 * 512;
  base[2] = wsh + XL_OFF + (bm * 32 + c) * 512 + (q << 3);
  base[3] = base[2] + 16 * 512;
  base[4] = wsh + WTH_OFF + (bn * 32 + c) * 512 + (q << 3);
  base[5] = base[4] + 16 * 512;
  base[6] = wsh + WTL_OFF + (bn * 32 + c) * 512 + (q << 3);
  base[7] = base[6] + 16 * 512;

  const v4f z = {0.f, 0.f, 0.f, 0.f};
  v4f a00 = z, a01 = z, a10 = z, a11 = z;

  v8s cur[8], nxt[8];
#pragma unroll
  for (int i = 0; i < 8; ++i) cur[i] = *(const v8s*)(base[i]);
#pragma unroll
  for (int i = 0; i < 8; ++i) nxt[i] = *(const v8s*)(base[i] + 32);

#pragma unroll 1
  for (int ks = 0; ks < 16; ++ks) {
    v8s nx2[8];
    if (ks < 14) {
      const int o = (ks + 2) * 32;
#pragma unroll
      for (int i = 0; i < 8; ++i) nx2[i] = *(const v8s*)(base[i] + o);
    }
    // Ah0,Ah1,Al0,Al1 = cur[0..3]; Bh0,Bh1,Bl0,Bl1 = cur[4..7]
    a00 = MFMA32(cur[2], cur[4], a00); a00 = MFMA32(cur[0], cur[6], a00); a00 = MFMA32(cur[0], cur[4], a00);
    a01 = MFMA32(cur[2], cur[5], a01); a01 = MFMA32(cur[0], cur[7], a01); a01 = MFMA32(cur[0], cur[5], a01);
    a10 = MFMA32(cur[3], cur[4], a10); a10 = MFMA32(cur[1], cur[6], a10); a10 = MFMA32(cur[1], cur[4], a10);
    a11 = MFMA32(cur[3], cur[5], a11); a11 = MFMA32(cur[1], cur[7], a11); a11 = MFMA32(cur[1], cur[5], a11);
#pragma unroll
    for (int i = 0; i < 8; ++i) { cur[i] = nxt[i]; nxt[i] = nx2[i]; }
  }

  v4f accs[2][2] = {{a00, a01}, {a10, a11}};
#pragma unroll
  for (int mt = 0; mt < 2; ++mt) {
#pragma unroll
    for (int nt = 0; nt < 2; ++nt) {
      const int n = bn * 32 + nt * 16 + c;
      const int which = n >> 9, cc = n & 511, h = cc >> 6, d = cc & 63;
      const float bv = bin[n];
#pragma unroll
      for (int r = 0; r < 4; ++r) {
        const int m = bm * 32 + mt * 16 + (q << 2) + r;
        const int b = (m >= 192) ? 1 : 0;
        const int tt = m - (b ? 192 : 0);
        const int bh = b * 8 + h;
        const float val = accs[mt][nt][r] + bv;
        const int rm = ((bh * 192 + tt) << 6) + d;
        if (which == 0)      wsf[rm] = val * QSCALE;
        else if (which == 1) wshd[rm] = f2bf(val);
        else if (which == 2) wshd[393216 + ((bh << 6) + d) * 192 + v1perm(tt)] = f2bf(val);
        else if (which == 3) wshd[196608 + rm] = f2bf(val);
        else wsf[196608 + ((bh * 192 + tt) * 16 + (d & 15)) * 4 + (d >> 4)] = val;
      }
    }
  }
}

// ------------------------------ Phase 2: attention -------------------------
// grid = 16(bh)*12(i)*4(ksplit) = 768 blocks, 256 thr (4 waves).
// Per wave: 6 kstep-PAIRS; per pair: batched L-MFMA/exp/pack, shared V1 frag
// reads feed both ksteps' PV. S accumulated via MFMA with ones-B.
// k2 read direct from global (transient regs, 16-lane broadcast, L2-hit).
// LDS 52224 => 3 blocks/CU (LDS-limited); grid 768 fully resident.
// launch_bounds(256,2): do NOT request 3 waves/EU -- that makes hipcc cap
// arch VGPRs at ~84 and spill k1f (R5/R6: 200-260MB scratch traffic).
__global__ __launch_bounds__(256, 2) void attn_kernel(
    const float* __restrict__ wsf, const unsigned short* __restrict__ wsh,
    float* __restrict__ accp, float* __restrict__ Sp) {
  __shared__ char smem[52224];
  unsigned short* V1s = (unsigned short*)smem;            // [64][200]

  const int tid  = threadIdx.x;
  const int wv   = tid >> 6;
  const int lane = tid & 63;
  const int c    = lane & 15;
  const int quad = lane >> 4;

  const int bb = blockIdx.x;
  const int kb = bb & 3;
  const int it = (bb >> 2) % 12;
  const int bh = bb / 48;

  const unsigned short* k1g = wsh + bh * 192 * 64;
  const unsigned short* v1g = wsh + 393216 + bh * 64 * 192;
  const unsigned short* k2g = wsh + 196608 + bh * 192 * 64;
  const float*          v2g = wsf + 196608 + bh * 12288;   // [192][16][4]

  // stage V1^T (permuted cols, stride 200)
  for (int idx = tid; idx < 1536; idx += 256) {
    const int r = idx / 24, c8 = (idx % 24) * 8;
    *(uint4*)(V1s + r * 200 + c8) = *(const uint4*)(v1g + r * 192 + c8);
  }

  // K1 B-frags resident in VGPRs: frag[jt][h] = K1[jt*16+c][h*32 + quad*8 ..+8]
  v8s k1f[12][2];
#pragma unroll
  for (int jt = 0; jt < 12; ++jt) {
    const unsigned short* kp = k1g + ((jt * 16 + c) << 6) + (quad << 3);
    k1f[jt][0] = *(const v8s*)(kp);
    k1f[jt][1] = *(const v8s*)(kp + 32);
  }

  // q rows (fp32, pre-scaled): i = it*16+c, d = quad*8+e (+32)
  const float* qg = wsf + ((bh * 192 + it * 16 + c) << 6) + (quad << 3);
  float q0[8], q1[8];
  {
    v4f qa = *(const v4f*)(qg), qb = *(const v4f*)(qg + 4);
    v4f qc = *(const v4f*)(qg + 32), qd = *(const v4f*)(qg + 36);
#pragma unroll
    for (int e = 0; e < 4; ++e) {
      q0[e] = qa[e]; q0[4 + e] = qb[e];
      q1[e] = qc[e]; q1[4 + e] = qd[e];
    }
  }
  __syncthreads();   // staging done; no barriers until epilogue

  unsigned* Pw = (unsigned*)(smem + 25600) + wv * 1664;  // [2 kk][16 i][52 dw]
  const v4f z = {0.f, 0.f, 0.f, 0.f};
  v4f acc[4] = {z, z, z, z};
  v4f oSA = z, oSB = z;
  const short one = (short)0x3F80;
  const v8s ones = {one, one, one, one, one, one, one, one};

  const int kloc0 = wv * 12;
  // per-wave global base for this wave's k2 rows (row 0 = kb*48 + kloc0)
  const unsigned short* k2r = k2g + ((kb * 48 + kloc0) << 6) + (quad << 3);
  union U4 { uint4 u4; unsigned short us[8]; };
  union AF { v8s v; unsigned u[4]; };

#pragma unroll 1
  for (int p = 0; p < 6; ++p) {
    const int rA = kloc0 + 2 * p, rB = rA + 1;
    U4 klA, khA, klB, khB;
    klA.u4 = *(const uint4*)(k2r + p * 128);
    khA.u4 = *(const uint4*)(k2r + p * 128 + 32);
    klB.u4 = *(const uint4*)(k2r + p * 128 + 64);
    khB.u4 = *(const uint4*)(k2r + p * 128 + 96);
    const v4f v2A = *(const v4f*)(v2g + (((kb * 48 + rA) << 4) + c) * 4);
    const v4f v2B = *(const v4f*)(v2g + (((kb * 48 + rB) << 4) + c) * 4);

    AF af[2][2];  // [kk][half]
#pragma unroll
    for (int e = 0; e < 4; ++e) {
      af[0][0].u[e] = pack_bf16(q0[2*e] * bf2f(klA.us[2*e]), q0[2*e+1] * bf2f(klA.us[2*e+1]));
      af[0][1].u[e] = pack_bf16(q1[2*e] * bf2f(khA.us[2*e]), q1[2*e+1] * bf2f(khA.us[2*e+1]));
      af[1][0].u[e] = pack_bf16(q0[2*e] * bf2f(klB.us[2*e]), q0[2*e+1] * bf2f(klB.us[2*e+1]));
      af[1][1].u[e] = pack_bf16(q1[2*e] * bf2f(khB.us[2*e]), q1[2*e+1] * bf2f(khB.us[2*e+1]));
    }

    v4f oA[4] = {z, z, z, z}, oB[4] = {z, z, z, z};

#pragma unroll
    for (int h = 0; h < 2; ++h) {
      // logits + exp + packed P-writes, kstep A then B
#pragma unroll
      for (int kk = 0; kk < 2; ++kk) {
        v4f C[6];
#pragma unroll
        for (int jj = 0; jj < 6; ++jj) {
          const int jt = h * 6 + jj;
          v4f t0 = MFMA32(af[kk][0].v, k1f[jt][0], z);
          C[jj] = MFMA32(af[kk][1].v, k1f[jt][1], t0);
        }
#pragma unroll
        for (int jj = 0; jj < 6; ++jj)
#pragma unroll
          for (int r = 0; r < 4; ++r) C[jj][r] = EXP2F(C[jj][r]);
#pragma unroll
        for (int m = 0; m < 3; ++m)
#pragma unroll
          for (int r = 0; r < 4; ++r)
            Pw[kk * 832 + ((quad << 2) + r) * 52 + m * 16 + c] =
                pack_bf16(C[2*m][r], C[2*m+1][r]);
      }
      // PV over the 96 j just produced; V1 frags shared by A and B
#pragma unroll
      for (int m = 0; m < 3; ++m) {
        const v8s apA = *(const v8s*)(Pw + c * 52 + m * 16 + (quad << 2));
        const v8s apB = *(const v8s*)(Pw + 832 + c * 52 + m * 16 + (quad << 2));
        oSA = MFMA32(apA, ones, oSA);
        oSB = MFMA32(apB, ones, oSB);
        const int vcol = (h * 3 + m) * 32 + (quad << 3);
#pragma unroll
        for (int t = 0; t < 4; ++t) {
          const v8s vf = *(const v8s*)(V1s + (c + 16 * t) * 200 + vcol);
          oA[t] = MFMA32(apA, vf, oA[t]);
          oB[t] = MFMA32(apB, vf, oB[t]);
        }
      }
    }
#pragma unroll
    for (int t = 0; t < 4; ++t) acc[t] += oA[t] * v2A[t] + oB[t] * v2B[t];
  }

  __syncthreads();  // reuse smem for cross-wave reduction
  float* redA = (float*)smem;              // [4][16][64]
  float* redS = (float*)smem + 4096;       // [4][16]

  if (c == 0) {
    float* rs = redS + wv * 16 + (quad << 2);
#pragma unroll
    for (int r = 0; r < 4; ++r) rs[r] = oSA[r] + oSB[r];
  }
#pragma unroll
  for (int r = 0; r < 4; ++r) {
    float* rr = redA + wv * 1024 + (((quad << 2) + r) << 6) + c;
    rr[0] = acc[0][r]; rr[16] = acc[1][r]; rr[32] = acc[2][r]; rr[48] = acc[3][r];
  }
  __syncthreads();

  const int pbase = (bh * 12 + it) * 4 + kb;
  float* ap_out = accp + pbase * 1024;
  for (int idx = tid; idx < 1024; idx += 256)
    ap_out[idx] = redA[idx] + redA[1024 + idx] + redA[2048 + idx] + redA[3072 + idx];
  if (tid < 16)
    Sp[pbase * 16 + tid] = redS[tid] + redS[16 + tid] + redS[32 + tid] + redS[48 + tid];
}

// ------------------------------ Phase 2.5: normalize -----------------------
__global__ __launch_bounds__(256) void norm_kernel(
    const float* __restrict__ accp, const float* __restrict__ Sp,
    unsigned short* __restrict__ wsh) {
  const int flat = blockIdx.x * 2048 + threadIdx.x * 8;
  const int m = flat >> 9, cc = flat & 511;
  const int b = (m >= 192) ? 1 : 0;
  const int tt = m - (b ? 192 : 0);
  const int h = cc >> 6, d0 = cc & 63;
  const int bh = b * 8 + h, it = tt >> 4, i = tt & 15;
  const int pb = (bh * 12 + it) * 4;
  const float* ap = accp + pb * 1024 + (i << 6) + d0;
  v4f a0 = *(const v4f*)(ap), a1 = *(const v4f*)(ap + 4);
  float Sv = Sp[pb * 16 + i];
#pragma unroll
  for (int kb = 1; kb < 4; ++kb) {
    a0 += *(const v4f*)(ap + kb * 1024);
    a1 += *(const v4f*)(ap + kb * 1024 + 4);
    Sv += Sp[(pb + kb) * 16 + i];
  }
  const float inv = 1.0f / Sv;
  union { uint4 u; unsigned short us[8]; } ph, pl;
#pragma unroll
  for (int j = 0; j < 4; ++j) {
    float v = a0[j] * inv;
    unsigned short hh = f2bf(v);
    ph.us[j] = hh; pl.us[j] = f2bf(v - bf2f(hh));
    v = a1[j] * inv;
    hh = f2bf(v);
    ph.us[4 + j] = hh; pl.us[4 + j] = f2bf(v - bf2f(hh));
  }
  *(uint4*)(wsh + OH_OFF + flat) = ph.u;
  *(uint4*)(wsh + OL_OFF + flat) = pl.u;
}

// ------------------------------ Phase 3: out GEMM (bf16x3 MFMA) ------------
// grid 192 x 64thr: M=384 (12), N=512 (16), K=512, prefetch depth 2.
__global__ __launch_bounds__(64) void outp_kernel(
    const unsigned short* __restrict__ wsh, const float* __restrict__ bout,
    float* __restrict__ y) {
  const int lane = threadIdx.x;
  const int c = lane & 15, q = lane >> 4;
  const int bm = blockIdx.x % 12, bn = blockIdx.x / 12;

  const unsigned short* base[8];
  base[0] = wsh + OH_OFF + (bm * 32 + c) * 512 + (q << 3);
  base[1] = base[0] + 16 * 512;
  base[2] = wsh + OL_OFF + (bm * 32 + c) * 512 + (q << 3);
  base[3] = base[2] + 16 * 512;
  base[4] = wsh + WOTH_OFF + (bn * 32 + c) * 512 + (q << 3);
  base[5] = base[4] + 16 * 512;
  base[6] = wsh + WOTL_OFF + (bn * 32 + c) * 512 + (q << 3);
  base[7] = base[6] + 16 * 512;

  const v4f z = {0.f, 0.f, 0.f, 0.f};
  v4f a00 = z, a01 = z, a10 = z, a11 = z;

  v8s cur[8], nxt[8];
#pragma unroll
  for (int i = 0; i < 8; ++i) cur[i] = *(const v8s*)(base[i]);
#pragma unroll
  for (int i = 0; i < 8; ++i) nxt[i] = *(const v8s*)(base[i] + 32);

#pragma unroll 1
  for (int ks = 0; ks < 16; ++ks) {
    v8s nx2[8];
    if (ks < 14) {
      const int o = (ks + 2) * 32;
#pragma unroll
      for (int i = 0; i < 8; ++i) nx2[i] = *(const v8s*)(base[i] + o);
    }
    a00 = MFMA32(cur[2], cur[4], a00); a00 = MFMA32(cur[0], cur[6], a00); a00 = MFMA32(cur[0], cur[4], a00);
    a01 = MFMA32(cur[2], cur[5], a01); a01 = MFMA32(cur[0], cur[7], a01); a01 = MFMA32(cur[0], cur[5], a01);
    a10 = MFMA32(cur[3], cur[4], a10); a10 = MFMA32(cur[1], cur[6], a10); a10 = MFMA32(cur[1], cur[4], a10);
    a11 = MFMA32(cur[3], cur[5], a11); a11 = MFMA32(cur[1], cur[7], a11); a11 = MFMA32(cur[1], cur[5], a11);
#pragma unroll
    for (int i = 0; i < 8; ++i) { cur[i] = nxt[i]; nxt[i] = nx2[i]; }
  }

  v4f accs[2][2] = {{a00, a01}, {a10, a11}};
#pragma unroll
  for (int mt = 0; mt < 2; ++mt) {
#pragma unroll
    for (int nt = 0; nt < 2; ++nt) {
      const int n = bn * 32 + nt * 16 + c;
      const float bv = bout[n];
#pragma unroll
      for (int r = 0; r < 4; ++r) {
        const int m = bm * 32 + mt * 16 + (q << 2) + r;
        y[m * 512 + n] = accs[mt][nt][r] + bv;
      }
    }
  }
}

// ------------------------------ launcher -----------------------------------
extern "C" void kernel_launch(void* const* d_in, const int* in_sizes, int n_in,
                              void* d_out, int out_size, void* d_ws, size_t ws_size,
                              hipStream_t stream) {
  const float* x    = (const float*)d_in[0];
  const float* Win  = (const float*)d_in[1];
  const float* bin  = (const float*)d_in[2];
  const float* Wout = (const float*)d_in[3];
  const float* bout = (const float*)d_in[4];

  float* wsf = (float*)d_ws;
  unsigned short* wsh = (unsigned short*)(wsf + 1191936);
  float* accp = wsf + 393216;
  float* Sp   = wsf + 1179648;

  prep_kernel<<<dim3(864), 256, 0, stream>>>(x, Win, Wout, wsh);
  proj_kernel<<<dim3(960), 64, 0, stream>>>(wsh, bin, wsf, wsh);
  attn_kernel<<<dim3(768), 256, 0, stream>>>(wsf, wsh, accp, Sp);
  norm_kernel<<<dim3(96), 256, 0, stream>>>(accp, Sp, wsh);
  outp_kernel<<<dim3(192), 64, 0, stream>>>(wsh, bout, (float*)d_out);
}

// Round 4
// 146.357 us; speedup vs baseline: 1.4289x; 1.0255x over previous
//
#include <hip/hip_runtime.h>
#include <hip/hip_bf16.h>

// ---------------------------------------------------------------------------
// TwoSimplicialAttention  (B=2, T=192, C=512, H=8, D=64)
// R8: attn LDS cut to 41984 B to fit 3 blocks/CU under the observed ~128 KiB
//     schedulable-LDS limit (R7: 52224 B still gave only 2 blocks/CU).
//     - K2s staging RESTORED (R7's k2-from-global cost ~5 us).
//     - Pw shrunk 26624 -> 10240 B: per-m-block write->read turnaround
//       (wave-synchronous per-wave buffer; holds ONE m at a time, both kk).
//       Costs both ksteps' exp'd C live at once (+~24 VGPR, no spill under
//       launch_bounds(256,2); 3 waves/SIMD still OK).
//     Grid 768 = 3*256 -> fully resident single pass.
// ---------------------------------------------------------------------------

typedef float  v4f __attribute__((ext_vector_type(4)));
typedef short  v8s __attribute__((ext_vector_type(8)));

__device__ __forceinline__ unsigned short f2bf(float f) {
  unsigned u = __float_as_uint(f);
  u += 0x7fffu + ((u >> 16) & 1u);       // RNE
  return (unsigned short)(u >> 16);
}
__device__ __forceinline__ float bf2f(unsigned short b) {
  return __uint_as_float(((unsigned)b) << 16);
}
__device__ __forceinline__ unsigned pack_bf16(float lo, float hi) {
  __hip_bfloat162 t = __float22bfloat162_rn(float2{lo, hi});
  union { __hip_bfloat162 b; unsigned u; } cv;
  cv.b = t;
  return cv.u;
}

#if __has_builtin(__builtin_amdgcn_exp2f)
#define EXP2F(x) __builtin_amdgcn_exp2f(x)
#else
#define EXP2F(x) exp2f(x)
#endif

#define MFMA32(a, b, c) __builtin_amdgcn_mfma_f32_16x16x32_bf16((a), (b), (c), 0, 0, 0)

// q scale = D^-0.5 * log2(e)
#define QSCALE 0.18033688011112042f

// ws layout, floats (wsf):
//   qs   [16][192][64]        @ 0        (q * 0.125*log2e, fp32)
//   v2p  [16][192][16][4]     @ 196608   ([.][k][c][r] = v2[d=c+16r], fp32)
//   accp [16][12][4][16][64]  @ 393216
//   Sp   [16][12][4][16]      @ 1179648  (total fp32: 1191936)
// ws layout, ushort (wsh = wsf + 1191936):
//   k1b  [16][192][64]  @ 0
//   k2b  [16][192][64]  @ 196608
//   v1t  [16][64][192]  @ 393216   (columns PERMUTED within 32-chunks)
//   xh   [384][512]     @ 589824      xl @ 786432
//   Wth  [2560][512]    @ 983040      Wtl @ 2293760   (W_in^T, k-major)
//   Woth [512][512]     @ 3604480     Wotl @ 3866624  (W_out^T, k-major)
//   oh   [384][512]     @ 4128768     ol  @ 4325376   (normalized out)

#define XH_OFF   589824
#define XL_OFF   786432
#define WTH_OFF  983040
#define WTL_OFF  2293760
#define WOTH_OFF 3604480
#define WOTL_OFF 3866624
#define OH_OFF   4128768
#define OL_OFF   4325376

// V1 column permutation within a 32-chunk: position p' for j-offset w5:
//   p' = ((w5>>2)&3)<<3 | (w5&3)<<1 | ((w5>>4)&1)
__device__ __forceinline__ int v1perm(int t) {
  return (t & ~31) | (((t >> 2) & 3) << 3) | ((t & 3) << 1) | ((t >> 4) & 1);
}

// ------------------------------ Phase 0: prep ------------------------------
// grid 864: [0,640) W_in transpose+split (64n x 32k tiles), [640,768) W_out,
// [768,864) x hi/lo split. W goes through LDS so global writes are dense.
__global__ __launch_bounds__(256) void prep_kernel(
    const float* __restrict__ x, const float* __restrict__ Win,
    const float* __restrict__ Wout, unsigned short* __restrict__ wsh) {
  __shared__ float tile[32 * 65];
  const int bi = blockIdx.x, t = threadIdx.x;
  if (bi < 768) {
    const float* W; unsigned short *Th, *Tl; int R, n0, k0;
    if (bi < 640) {
      W = Win; Th = wsh + WTH_OFF; Tl = wsh + WTL_OFF; R = 2560;
      n0 = (bi % 40) << 6; k0 = (bi / 40) << 5;
    } else {
      const int idx = bi - 640;
      W = Wout; Th = wsh + WOTH_OFF; Tl = wsh + WOTL_OFF; R = 512;
      n0 = (idx & 7) << 6; k0 = (idx >> 3) << 5;
    }
    // phase 1: coalesced reads -> LDS [k][n] (pad 65)
    const int n = t & 63, kq = (t >> 6) * 8;
#pragma unroll
    for (int j = 0; j < 8; ++j)
      tile[(kq + j) * 65 + n] = W[(k0 + kq + j) * R + n0 + n];
    __syncthreads();
    // phase 2: k-contig hi/lo writes (dense 64B lines)
    const int n2 = t >> 2, ks = (t & 3) * 8;
    union { uint4 u; unsigned short us[8]; } ph, pl;
#pragma unroll
    for (int j = 0; j < 8; ++j) {
      const float v = tile[(ks + j) * 65 + n2];
      const unsigned short h = f2bf(v);
      ph.us[j] = h;
      pl.us[j] = f2bf(v - bf2f(h));
    }
    *(uint4*)(Th + (n0 + n2) * 512 + k0 + ks) = ph.u;
    *(uint4*)(Tl + (n0 + n2) * 512 + k0 + ks) = pl.u;
  } else {
    const int flat = ((bi - 768) * 256 + t) * 8;
    const v4f v0 = *(const v4f*)(x + flat);
    const v4f v1 = *(const v4f*)(x + flat + 4);
    union { uint4 u; unsigned short us[8]; } ph, pl;
#pragma unroll
    for (int j = 0; j < 4; ++j) {
      unsigned short h = f2bf(v0[j]);
      ph.us[j] = h; pl.us[j] = f2bf(v0[j] - bf2f(h));
      h = f2bf(v1[j]);
      ph.us[4 + j] = h; pl.us[4 + j] = f2bf(v1[j] - bf2f(h));
    }
    *(uint4*)(wsh + XH_OFF + flat) = ph.u;
    *(uint4*)(wsh + XL_OFF + flat) = pl.u;
  }
}

// ------------------------------ Phase 1: proj (bf16x3 MFMA) ----------------
// grid 960 x 64thr: 1 wave/block, 32x32 C-tile, prefetch depth 2.
__global__ __launch_bounds__(64) void proj_kernel(
    const unsigned short* __restrict__ wsh, const float* __restrict__ bin,
    float* __restrict__ wsf, unsigned short* __restrict__ wshd) {
  const int lane = threadIdx.x;
  const int c = lane & 15, q = lane >> 4;
  const int bm = blockIdx.x % 12, bn = blockIdx.x / 12;

  const unsigned short* base[8];
  base[0] = wsh + XH_OFF + (bm * 32 + c) * 512 + (q << 3);
  base[1] = base[0] + 16 * 512;
  base[2] = wsh + XL_OFF + (bm * 32 + c) * 512 + (q << 3);
  base[3] = base[2] + 16 * 512;
  base[4] = wsh + WTH_OFF + (bn * 32 + c) * 512 + (q << 3);
  base[5] = base[4] + 16 * 512;
  base[6] = wsh + WTL_OFF + (bn * 32 + c) * 512 + (q << 3);
  base[7] = base[6] + 16 * 512;

  const v4f z = {0.f, 0.f, 0.f, 0.f};
  v4f a00 = z, a01 = z, a10 = z, a11 = z;

  v8s cur[8], nxt[8];
#pragma unroll
  for (int i = 0; i < 8; ++i) cur[i] = *(const v8s*)(base[i]);
#pragma unroll
  for (int i = 0; i < 8; ++i) nxt[i] = *(const v8s*)(base[i] + 32);

#pragma unroll 1
  for (int ks = 0; ks < 16; ++ks) {
    v8s nx2[8];
    if (ks < 14) {
      const int o = (ks + 2) * 32;
#pragma unroll
      for (int i = 0; i < 8; ++i) nx2[i] = *(const v8s*)(base[i] + o);
    }
    // Ah0,Ah1,Al0,Al1 = cur[0..3]; Bh0,Bh1,Bl0,Bl1 = cur[4..7]
    a00 = MFMA32(cur[2], cur[4], a00); a00 = MFMA32(cur[0], cur[6], a00); a00 = MFMA32(cur[0], cur[4], a00);
    a01 = MFMA32(cur[2], cur[5], a01); a01 = MFMA32(cur[0], cur[7], a01); a01 = MFMA32(cur[0], cur[5], a01);
    a10 = MFMA32(cur[3], cur[4], a10); a10 = MFMA32(cur[1], cur[6], a10); a10 = MFMA32(cur[1], cur[4], a10);
    a11 = MFMA32(cur[3], cur[5], a11); a11 = MFMA32(cur[1], cur[7], a11); a11 = MFMA32(cur[1], cur[5], a11);
#pragma unroll
    for (int i = 0; i < 8; ++i) { cur[i] = nxt[i]; nxt[i] = nx2[i]; }
  }

  v4f accs[2][2] = {{a00, a01}, {a10, a11}};
#pragma unroll
  for (int mt = 0; mt < 2; ++mt) {
#pragma unroll
    for (int nt = 0; nt < 2; ++nt) {
      const int n = bn * 32 + nt * 16 + c;
      const int which = n >> 9, cc = n & 511, h = cc >> 6, d = cc & 63;
      const float bv = bin[n];
#pragma unroll
      for (int r = 0; r < 4; ++r) {
        const int m = bm * 32 + mt * 16 + (q << 2) + r;
        const int b = (m >= 192) ? 1 : 0;
        const int tt = m - (b ? 192 : 0);
        const int bh = b * 8 + h;
        const float val = accs[mt][nt][r] + bv;
        const int rm = ((bh * 192 + tt) << 6) + d;
        if (which == 0)      wsf[rm] = val * QSCALE;
        else if (which == 1) wshd[rm] = f2bf(val);
        else if (which == 2) wshd[393216 + ((bh << 6) + d) * 192 + v1perm(tt)] = f2bf(val);
        else if (which == 3) wshd[196608 + rm] = f2bf(val);
        else wsf[196608 + ((bh * 192 + tt) * 16 + (d & 15)) * 4 + (d >> 4)] = val;
      }
    }
  }
}

// ------------------------------ Phase 2: attention -------------------------
// grid = 16(bh)*12(i)*4(ksplit) = 768 blocks, 256 thr (4 waves).
// Per wave: 6 kstep-PAIRS; per pair: batched L-MFMA (both kk) -> exp x48 ->
// per-m {packed P-writes (both kk), P-read, PV}. Pw holds one m-block at a
// time (wave-synchronous turnaround) => 2560 B/wave.
// LDS: V1s 25600 + K2s 6144 + Pw 10240 = 41984 B => 3 blocks/CU.
// launch_bounds(256,2): (256,3) caps arch VGPRs at ~84 and spills (R5/R6).
__global__ __launch_bounds__(256, 2) void attn_kernel(
    const float* __restrict__ wsf, const unsigned short* __restrict__ wsh,
    float* __restrict__ accp, float* __restrict__ Sp) {
  __shared__ char smem[41984];
  unsigned short* V1s = (unsigned short*)smem;            // [64][200]
  unsigned short* K2s = (unsigned short*)(smem + 25600);  // [48][64]

  const int tid  = threadIdx.x;
  const int wv   = tid >> 6;
  const int lane = tid & 63;
  const int c    = lane & 15;
  const int quad = lane >> 4;

  const int bb = blockIdx.x;
  const int kb = bb & 3;
  const int it = (bb >> 2) % 12;
  const int bh = bb / 48;

  const unsigned short* k1g = wsh + bh * 192 * 64;
  const unsigned short* v1g = wsh + 393216 + bh * 64 * 192;
  const unsigned short* k2g = wsh + 196608 + bh * 192 * 64;
  const float*          v2g = wsf + 196608 + bh * 12288;   // [192][16][4]

  // stage V1^T (permuted cols, stride 200) and this block's 48 k2 rows
  for (int idx = tid; idx < 1920; idx += 256) {
    if (idx < 1536) {
      const int r = idx / 24, c8 = (idx % 24) * 8;
      *(uint4*)(V1s + r * 200 + c8) = *(const uint4*)(v1g + r * 192 + c8);
    } else {
      const int j = idx - 1536;
      const int r = j >> 3, c8 = (j & 7) * 8;
      *(uint4*)(K2s + r * 64 + c8) = *(const uint4*)(k2g + (kb * 48 + r) * 64 + c8);
    }
  }

  // K1 B-frags resident in VGPRs: frag[jt][h] = K1[jt*16+c][h*32 + quad*8 ..+8]
  v8s k1f[12][2];
#pragma unroll
  for (int jt = 0; jt < 12; ++jt) {
    const unsigned short* kp = k1g + ((jt * 16 + c) << 6) + (quad << 3);
    k1f[jt][0] = *(const v8s*)(kp);
    k1f[jt][1] = *(const v8s*)(kp + 32);
  }

  // q rows (fp32, pre-scaled): i = it*16+c, d = quad*8+e (+32)
  const float* qg = wsf + ((bh * 192 + it * 16 + c) << 6) + (quad << 3);
  float q0[8], q1[8];
  {
    v4f qa = *(const v4f*)(qg), qb = *(const v4f*)(qg + 4);
    v4f qc = *(const v4f*)(qg + 32), qd = *(const v4f*)(qg + 36);
#pragma unroll
    for (int e = 0; e < 4; ++e) {
      q0[e] = qa[e]; q0[4 + e] = qb[e];
      q1[e] = qc[e]; q1[4 + e] = qd[e];
    }
  }
  __syncthreads();   // staging done; no barriers until epilogue

  // Pw: per-wave [2 kk][16 rows][20 dw] -- holds ONE m-block at a time
  unsigned* Pw = (unsigned*)(smem + 31744) + wv * 640;
  const v4f z = {0.f, 0.f, 0.f, 0.f};
  v4f acc[4] = {z, z, z, z};
  v4f oSA = z, oSB = z;
  const short one = (short)0x3F80;
  const v8s ones = {one, one, one, one, one, one, one, one};

  const int kloc0 = wv * 12;
  union U4 { uint4 u4; unsigned short us[8]; };
  union AF { v8s v; unsigned u[4]; };

#pragma unroll 1
  for (int p = 0; p < 6; ++p) {
    const int rA = kloc0 + 2 * p, rB = rA + 1;
    U4 klA, khA, klB, khB;
    klA.u4 = *(const uint4*)(K2s + rA * 64 + (quad << 3));
    khA.u4 = *(const uint4*)(K2s + rA * 64 + (quad << 3) + 32);
    klB.u4 = *(const uint4*)(K2s + rB * 64 + (quad << 3));
    khB.u4 = *(const uint4*)(K2s + rB * 64 + (quad << 3) + 32);
    const v4f v2A = *(const v4f*)(v2g + (((kb * 48 + rA) << 4) + c) * 4);
    const v4f v2B = *(const v4f*)(v2g + (((kb * 48 + rB) << 4) + c) * 4);

    AF af[2][2];  // [kk][half]
#pragma unroll
    for (int e = 0; e < 4; ++e) {
      af[0][0].u[e] = pack_bf16(q0[2*e] * bf2f(klA.us[2*e]), q0[2*e+1] * bf2f(klA.us[2*e+1]));
      af[0][1].u[e] = pack_bf16(q1[2*e] * bf2f(khA.us[2*e]), q1[2*e+1] * bf2f(khA.us[2*e+1]));
      af[1][0].u[e] = pack_bf16(q0[2*e] * bf2f(klB.us[2*e]), q0[2*e+1] * bf2f(klB.us[2*e+1]));
      af[1][1].u[e] = pack_bf16(q1[2*e] * bf2f(khB.us[2*e]), q1[2*e+1] * bf2f(khB.us[2*e+1]));
    }

    v4f oA[4] = {z, z, z, z}, oB[4] = {z, z, z, z};

#pragma unroll
    for (int h = 0; h < 2; ++h) {
      // logits for both ksteps (batched MFMA), then batched exp
      v4f C0[6], C1[6];
#pragma unroll
      for (int jj = 0; jj < 6; ++jj) {
        const int jt = h * 6 + jj;
        v4f t0 = MFMA32(af[0][0].v, k1f[jt][0], z);
        C0[jj] = MFMA32(af[0][1].v, k1f[jt][1], t0);
      }
#pragma unroll
      for (int jj = 0; jj < 6; ++jj) {
        const int jt = h * 6 + jj;
        v4f t0 = MFMA32(af[1][0].v, k1f[jt][0], z);
        C1[jj] = MFMA32(af[1][1].v, k1f[jt][1], t0);
      }
#pragma unroll
      for (int jj = 0; jj < 6; ++jj)
#pragma unroll
        for (int r = 0; r < 4; ++r) {
          C0[jj][r] = EXP2F(C0[jj][r]);
          C1[jj][r] = EXP2F(C1[jj][r]);
        }
      // per-m: write both kk's packed P, read back (wave-sync), PV
#pragma unroll
      for (int m = 0; m < 3; ++m) {
#pragma unroll
        for (int r = 0; r < 4; ++r) {
          Pw[((quad << 2) + r) * 20 + c]       = pack_bf16(C0[2*m][r], C0[2*m+1][r]);
          Pw[640 - 320 + ((quad << 2) + r) * 20 + c] = pack_bf16(C1[2*m][r], C1[2*m+1][r]);
        }
        const v8s apA = *(const v8s*)(Pw + c * 20 + (quad << 2));
        const v8s apB = *(const v8s*)(Pw + 320 + c * 20 + (quad << 2));
        oSA = MFMA32(apA, ones, oSA);
        oSB = MFMA32(apB, ones, oSB);
        const int vcol = (h * 3 + m) * 32 + (quad << 3);
#pragma unroll
        for (int t = 0; t < 4; ++t) {
          const v8s vf = *(const v8s*)(V1s + (c + 16 * t) * 200 + vcol);
          oA[t] = MFMA32(apA, vf, oA[t]);
          oB[t] = MFMA32(apB, vf, oB[t]);
        }
      }
    }
#pragma unroll
    for (int t = 0; t < 4; ++t) acc[t] += oA[t] * v2A[t] + oB[t] * v2B[t];
  }

  __syncthreads();  // reuse smem for cross-wave reduction
  float* redA = (float*)smem;              // [4][16][64]
  float* redS = (float*)smem + 4096;       // [4][16]

  if (c == 0) {
    float* rs = redS + wv * 16 + (quad << 2);
#pragma unroll
    for (int r = 0; r < 4; ++r) rs[r] = oSA[r] + oSB[r];
  }
#pragma unroll
  for (int r = 0; r < 4; ++r) {
    float* rr = redA + wv * 1024 + (((quad << 2) + r) << 6) + c;
    rr[0] = acc[0][r]; rr[16] = acc[1][r]; rr[32] = acc[2][r]; rr[48] = acc[3][r];
  }
  __syncthreads();

  const int pbase = (bh * 12 + it) * 4 + kb;
  float* ap_out = accp + pbase * 1024;
  for (int idx = tid; idx < 1024; idx += 256)
    ap_out[idx] = redA[idx] + redA[1024 + idx] + redA[2048 + idx] + redA[3072 + idx];
  if (tid < 16)
    Sp[pbase * 16 + tid] = redS[tid] + redS[16 + tid] + redS[32 + tid] + redS[48 + tid];
}

// ------------------------------ Phase 2.5: normalize -----------------------
__global__ __launch_bounds__(256) void norm_kernel(
    const float* __restrict__ accp, const float* __restrict__ Sp,
    unsigned short* __restrict__ wsh) {
  const int flat = blockIdx.x * 2048 + threadIdx.x * 8;
  const int m = flat >> 9, cc = flat & 511;
  const int b = (m >= 192) ? 1 : 0;
  const int tt = m - (b ? 192 : 0);
  const int h = cc >> 6, d0 = cc & 63;
  const int bh = b * 8 + h, it = tt >> 4, i = tt & 15;
  const int pb = (bh * 12 + it) * 4;
  const float* ap = accp + pb * 1024 + (i << 6) + d0;
  v4f a0 = *(const v4f*)(ap), a1 = *(const v4f*)(ap + 4);
  float Sv = Sp[pb * 16 + i];
#pragma unroll
  for (int kb = 1; kb < 4; ++kb) {
    a0 += *(const v4f*)(ap + kb * 1024);
    a1 += *(const v4f*)(ap + kb * 1024 + 4);
    Sv += Sp[(pb + kb) * 16 + i];
  }
  const float inv = 1.0f / Sv;
  union { uint4 u; unsigned short us[8]; } ph, pl;
#pragma unroll
  for (int j = 0; j < 4; ++j) {
    float v = a0[j] * inv;
    unsigned short hh = f2bf(v);
    ph.us[j] = hh; pl.us[j] = f2bf(v - bf2f(hh));
    v = a1[j] * inv;
    hh = f2bf(v);
    ph.us[4 + j] = hh; pl.us[4 + j] = f2bf(v - bf2f(hh));
  }
  *(uint4*)(wsh + OH_OFF + flat) = ph.u;
  *(uint4*)(wsh + OL_OFF + flat) = pl.u;
}

// ------------------------------ Phase 3: out GEMM (bf16x3 MFMA) ------------
// grid 192 x 64thr: M=384 (12), N=512 (16), K=512, prefetch depth 2.
__global__ __launch_bounds__(64) void outp_kernel(
    const unsigned short* __restrict__ wsh, const float* __restrict__ bout,
    float* __restrict__ y) {
  const int lane = threadIdx.x;
  const int c = lane & 15, q = lane >> 4;
  const int bm = blockIdx.x % 12, bn = blockIdx.x / 12;

  const unsigned short* base[8];
  base[0] = wsh + OH_OFF + (bm * 32 + c) * 512 + (q << 3);
  base[1] = base[0] + 16 * 512;
  base[2] = wsh + OL_OFF + (bm * 32 + c) * 512 + (q << 3);
  base[3] = base[2] + 16 * 512;
  base[4] = wsh + WOTH_OFF + (bn * 32 + c) * 512 + (q << 3);
  base[5] = base[4] + 16 * 512;
  base[6] = wsh + WOTL_OFF + (bn * 32 + c) * 512 + (q << 3);
  base[7] = base[6] + 16 * 512;

  const v4f z = {0.f, 0.f, 0.f, 0.f};
  v4f a00 = z, a01 = z, a10 = z, a11 = z;

  v8s cur[8], nxt[8];
#pragma unroll
  for (int i = 0; i < 8; ++i) cur[i] = *(const v8s*)(base[i]);
#pragma unroll
  for (int i = 0; i < 8; ++i) nxt[i] = *(const v8s*)(base[i] + 32);

#pragma unroll 1
  for (int ks = 0; ks < 16; ++ks) {
    v8s nx2[8];
    if (ks < 14) {
      const int o = (ks + 2) * 32;
#pragma unroll
      for (int i = 0; i < 8; ++i) nx2[i] = *(const v8s*)(base[i] + o);
    }
    a00 = MFMA32(cur[2], cur[4], a00); a00 = MFMA32(cur[0], cur[6], a00); a00 = MFMA32(cur[0], cur[4], a00);
    a01 = MFMA32(cur[2], cur[5], a01); a01 = MFMA32(cur[0], cur[7], a01); a01 = MFMA32(cur[0], cur[5], a01);
    a10 = MFMA32(cur[3], cur[4], a10); a10 = MFMA32(cur[1], cur[6], a10); a10 = MFMA32(cur[1], cur[4], a10);
    a11 = MFMA32(cur[3], cur[5], a11); a11 = MFMA32(cur[1], cur[7], a11); a11 = MFMA32(cur[1], cur[5], a11);
#pragma unroll
    for (int i = 0; i < 8; ++i) { cur[i] = nxt[i]; nxt[i] = nx2[i]; }
  }

  v4f accs[2][2] = {{a00, a01}, {a10, a11}};
#pragma unroll
  for (int mt = 0; mt < 2; ++mt) {
#pragma unroll
    for (int nt = 0; nt < 2; ++nt) {
      const int n = bn * 32 + nt * 16 + c;
      const float bv = bout[n];
#pragma unroll
      for (int r = 0; r < 4; ++r) {
        const int m = bm * 32 + mt * 16 + (q << 2) + r;
        y[m * 512 + n] = accs[mt][nt][r] + bv;
      }
    }
  }
}

// ------------------------------ launcher -----------------------------------
extern "C" void kernel_launch(void* const* d_in, const int* in_sizes, int n_in,
                              void* d_out, int out_size, void* d_ws, size_t ws_size,
                              hipStream_t stream) {
  const float* x    = (const float*)d_in[0];
  const float* Win  = (const float*)d_in[1];
  const float* bin  = (const float*)d_in[2];
  const float* Wout = (const float*)d_in[3];
  const float* bout = (const float*)d_in[4];

  float* wsf = (float*)d_ws;
  unsigned short* wsh = (unsigned short*)(wsf + 1191936);
  float* accp = wsf + 393216;
  float* Sp   = wsf + 1179648;

  prep_kernel<<<dim3(864), 256, 0, stream>>>(x, Win, Wout, wsh);
  proj_kernel<<<dim3(960), 64, 0, stream>>>(wsh, bin, wsf, wsh);
  attn_kernel<<<dim3(768), 256, 0, stream>>>(wsf, wsh, accp, Sp);
  norm_kernel<<<dim3(96), 256, 0, stream>>>(accp, Sp, wsh);
  outp_kernel<<<dim3(192), 64, 0, stream>>>(wsh, bout, (float*)d_out);
}